// Round 6
// baseline (219.812 us; speedup 1.0000x reference)
//
#include <hip/hip_runtime.h>
#include <math.h>

// Problem constants (fixed by setup_inputs): h [B=16, S=4096, D=512] fp32.
constexpr int B_ = 16;
constexpr int S_ = 4096;
constexpr int D_ = 512;
constexpr float MARGIN = 0.5f;
constexpr float EPS = 1e-8f;

constexpr int T_   = 8;               // owned t's per block
constexpr int ROWS = T_ + 19;         // 27 staged rows (own + halo)
constexpr int RSF  = 520;             // fp32 row stride; 520%32==8 -> even bank
                                      // spread for wave64 ds_read_b128 frags
constexpr int NBLK = B_ * (S_ / T_);  // 8192 blocks

typedef __attribute__((ext_vector_type(8))) short short8;   // 8 bf16 (4 VGPRs)
typedef __attribute__((ext_vector_type(4))) float floatx4;  // MFMA 16x16 acc

// v_add_f32_dpp step: x += dpp_move(x); bound_ctrl zero-fills invalid lanes.
template <int CTRL>
__device__ __forceinline__ float dpp_add(float x) {
    int m = __builtin_amdgcn_update_dpp(0, __float_as_int(x), CTRL, 0xf, 0xf, true);
    return x + __int_as_float(m);
}
// Full wave64 sum via DPP (pure VALU). Result valid in lane 63.
__device__ __forceinline__ float wave_sum63(float x) {
    x = dpp_add<0x111>(x);  // row_shr:1
    x = dpp_add<0x112>(x);  // row_shr:2
    x = dpp_add<0x114>(x);  // row_shr:4
    x = dpp_add<0x118>(x);  // row_shr:8
    x = dpp_add<0x142>(x);  // row_bcast:15
    x = dpp_add<0x143>(x);  // row_bcast:31
    return x;
}

// Read 8 fp32 from LDS (2x ds_read_b128), truncate to bf16 frag.
// (bf16-trunc correctness established in R4/R5: absmax 0.0.)
__device__ __forceinline__ short8 ldsfrag(const float* p) {
    float4 a = *(const float4*)p;
    float4 b = *(const float4*)(p + 4);
    short8 s;
    s[0] = (short)(__float_as_uint(a.x) >> 16);
    s[1] = (short)(__float_as_uint(a.y) >> 16);
    s[2] = (short)(__float_as_uint(a.z) >> 16);
    s[3] = (short)(__float_as_uint(a.w) >> 16);
    s[4] = (short)(__float_as_uint(b.x) >> 16);
    s[5] = (short)(__float_as_uint(b.y) >> 16);
    s[6] = (short)(__float_as_uint(b.z) >> 16);
    s[7] = (short)(__float_as_uint(b.w) >> 16);
    return s;
}

// Per block: DMA 27 fp32 rows (global_load_lds, 1 KB/instr, no VGPR round-trip,
// no pack VALU), one barrier, then 3 MFMA 16x16x32 Gram jobs:
//   j0 (w0): A rows 0..15  x B rows 0..15  -> sims cols [0,10], diag cols [0,15]
//   j1 (w1): A rows 0..15  x B rows 11..26 -> sims cols [11,26]
//   j2 (w2): A rows 11..26 x B rows 11..26 -> diag cols [16,26] (halo norms)
// Sim terms restricted to owned rows 0..7 (grow < T_) to avoid double count.
__global__ __launch_bounds__(256, 2) void tcl_partial(const float* __restrict__ h,
                                                      float* __restrict__ ws) {
    __shared__ float smf[ROWS * RSF];  // 56160 B
    __shared__ float norms[ROWS];
    __shared__ float bsum[4];

    const int tid  = threadIdx.x;
    const int lane = tid & 63;
    const int w    = tid >> 6;

    // XCD swizzle: consecutive logical strips land on the same XCD so the
    // 19-row halo re-reads hit that XCD's L2. (Round-robin p%8 assumption —
    // perf-only heuristic, correctness-neutral.)
    const int p  = blockIdx.x;
    const int L  = (p & 7) * 1024 + (p >> 3);
    const int b  = L >> 9;                // S/T = 512 strips per batch
    const int t0 = (L & 511) * T_;
    const float* base = h + (size_t)b * S_ * D_;

    // ---- Stage: 27 rows x 2 KB = 54 x 1 KB DMA chunks, spread over 4 waves ----
    for (int c = w; c < 2 * ROWS; c += 4) {
        const int r    = c >> 1;
        const int half = c & 1;
        const int t    = t0 + r;
        float* ldst = &smf[r * RSF + half * 256];
        if (t < S_) {
            const float* gsrc = base + (size_t)t * D_ + half * 256 + lane * 4;
            __builtin_amdgcn_global_load_lds(
                (__attribute__((address_space(1))) void*)(gsrc),
                (__attribute__((address_space(3))) void*)(ldst),
                16, 0, 0);
        } else {
            ((float4*)ldst)[lane] = make_float4(0.f, 0.f, 0.f, 0.f);
        }
    }
    __syncthreads();  // drains vmcnt (global_load_lds) before any LDS read

    const int m16 = lane & 15;
    const int q   = lane >> 4;
    const int q8  = q * 8;

    // ---- MFMA: wave w (<3) computes job w ----
    const int AR[3] = {0, 0, 11};
    const int BR[3] = {0, 11, 11};
    floatx4 acc = {0.f, 0.f, 0.f, 0.f};
    if (w < 3) {
        const float* pa = &smf[(AR[w] + m16) * RSF + q8];
        const float* pb = &smf[(BR[w] + m16) * RSF + q8];
#pragma unroll
        for (int kk = 0; kk < 16; ++kk) {
            short8 af = ldsfrag(pa + kk * 32);
            short8 bf = ldsfrag(pb + kk * 32);
            acc = __builtin_amdgcn_mfma_f32_16x16x32_bf16(af, bf, acc, 0, 0, 0);
        }
    }

    // ---- Diag -> norms[] (disjoint col windows: j0 [0,15], j2 [16,26]) ----
    if (w == 0) {
        const int gcol = m16;
#pragma unroll
        for (int r = 0; r < 4; ++r)
            if (q * 4 + r == gcol) norms[gcol] = sqrtf(acc[r]);
    } else if (w == 2) {
        const int gcol = 11 + m16;
        if (gcol >= 16) {
#pragma unroll
            for (int r = 0; r < 4; ++r)
                if (11 + q * 4 + r == gcol) norms[gcol] = sqrtf(acc[r]);
        }
    }
    __syncthreads();

    // ---- Sim terms (owned rows 0..7 only) ----
    const float w1 = 1.0f / ((float)B_ * (float)(S_ - 1));
    const float w2 = 1.0f / ((float)B_ * (float)(10 * S_ - 145));
    float local = 0.f;
    if (w == 0) {
        const int gcol = m16;
        if (gcol <= 10 && (t0 + gcol) < S_) {
            const float nb = norms[gcol];
#pragma unroll
            for (int r = 0; r < 4; ++r) {
                const int grow = q * 4 + r;
                const int k = gcol - grow;
                if (grow < T_ && (k == 1 || k == 10)) {
                    const float sim = acc[r] / fmaxf(norms[grow] * nb, EPS);
                    local += (k == 1) ? w1 * (1.0f - sim)
                                      : w2 * fmaxf(MARGIN - sim, 0.f);
                }
            }
        }
    } else if (w == 1) {
        const int gcol = 11 + m16;
        if ((t0 + gcol) < S_) {
            const float nb = norms[gcol];
#pragma unroll
            for (int r = 0; r < 4; ++r) {
                const int grow = q * 4 + r;
                const int k = gcol - grow;
                if (grow < T_ && k >= 10 && k <= 19) {
                    const float sim = acc[r] / fmaxf(norms[grow] * nb, EPS);
                    local += w2 * fmaxf(MARGIN - sim, 0.f);
                }
            }
        }
    }

    local = wave_sum63(local);
    if (lane == 63) bsum[w] = local;
    __syncthreads();
    if (tid == 0) ws[blockIdx.x] = bsum[0] + bsum[1] + bsum[2] + bsum[3];
}

__global__ __launch_bounds__(1024) void tcl_final(const float* __restrict__ ws,
                                                  float* __restrict__ out) {
    float v = 0.f;
    for (int j = threadIdx.x; j < NBLK; j += 1024) v += ws[j];
    v = wave_sum63(v);
    __shared__ float s[16];
    if ((threadIdx.x & 63) == 63) s[threadIdx.x >> 6] = v;
    __syncthreads();
    if (threadIdx.x == 0) {
        float t = 0.f;
#pragma unroll
        for (int j = 0; j < 16; j++) t += s[j];
        out[0] = t;
    }
}

extern "C" void kernel_launch(void* const* d_in, const int* in_sizes, int n_in,
                              void* d_out, int out_size, void* d_ws, size_t ws_size,
                              hipStream_t stream) {
    const float* h = (const float*)d_in[0];
    float* out = (float*)d_out;
    float* ws = (float*)d_ws;  // NBLK * 4 = 32 KB
    tcl_partial<<<NBLK, 256, 0, stream>>>(h, ws);
    tcl_final<<<1, 1024, 0, stream>>>(ws, out);
}

// Round 7
// 202.071 us; speedup vs baseline: 1.0878x; 1.0878x over previous
//
#include <hip/hip_runtime.h>
#include <math.h>

// Problem constants (fixed by setup_inputs): h [B=16, S=4096, D=512] fp32.
constexpr int B_ = 16;
constexpr int S_ = 4096;
constexpr int D_ = 512;
constexpr float MARGIN = 0.5f;
constexpr float EPS = 1e-8f;

constexpr int TGR = 32;                      // owned t's per wave
constexpr int WPB = 4;                       // waves per block
constexpr int NBLK = B_ * S_ / (TGR * WPB);  // 512 blocks (2 per CU)
constexpr int NW   = NBLK * WPB;             // 2048 waves

typedef __attribute__((ext_vector_type(8))) short short8;   // 8 bf16 (4 VGPRs)
typedef __attribute__((ext_vector_type(4))) float floatx4;  // MFMA 16x16 acc

// v_add_f32_dpp step: x += dpp_move(x); bound_ctrl zero-fills invalid lanes.
template <int CTRL>
__device__ __forceinline__ float dpp_add(float x) {
    int m = __builtin_amdgcn_update_dpp(0, __float_as_int(x), CTRL, 0xf, 0xf, true);
    return x + __int_as_float(m);
}
// Full wave64 sum via DPP (pure VALU). Result valid in lane 63.
__device__ __forceinline__ float wave_sum63(float x) {
    x = dpp_add<0x111>(x);  // row_shr:1
    x = dpp_add<0x112>(x);  // row_shr:2
    x = dpp_add<0x114>(x);  // row_shr:4
    x = dpp_add<0x118>(x);  // row_shr:8
    x = dpp_add<0x142>(x);  // row_bcast:15
    x = dpp_add<0x143>(x);  // row_bcast:31
    return x;
}

// Pack two fp32 into two bf16 (truncation — proven exact enough in R4-R6).
__device__ __forceinline__ unsigned int pk(float lo, float hi) {
    return (__float_as_uint(lo) >> 16) | (__float_as_uint(hi) & 0xffff0000u);
}

// Each wave is fully self-contained: owns rows [t0, t0+32), loads 4 row-frag
// sets (row offsets 0/16/32/48) STRAIGHT from global (no LDS staging — R4-R6
// showed every staged variant loses on occupancy/LDS-pipe/barriers), and
// computes 8 MFMA 16x16x32 Gram jobs per K-step:
//   sim tiles: (A0,B0) (A0,B1) (A0,B2) (A1,B1) (A1,B2) (A1,B3)
//   diag-only: f2xf2, f3xf3  (halo norms; owned diag comes from A0B0/A1B1)
// Norms are shared across lanes via a tiny per-wave LDS array (1 KB/block).
__global__ __launch_bounds__(256, 2) void tcl_partial(const float* __restrict__ h,
                                                      float* __restrict__ ws) {
    __shared__ float nlds[WPB][64];

    const int tid  = threadIdx.x;
    const int lane = tid & 63;
    const int w    = tid >> 6;

    // XCD swizzle: consecutive strips (halo-sharing neighbors) land on the
    // same XCD for L2 halo hits. Bijective for 512 blocks over 8 XCDs.
    const int p  = blockIdx.x;
    const int L  = (p & 7) * (NBLK / 8) + (p >> 3);
    const int gw = L * WPB + w;            // 0..2047
    const int b  = gw >> 7;                // 128 waves per batch (S/TGR)
    const int t0 = (gw & 127) * TGR;

    const int m16 = lane & 15;
    const int q   = lane >> 4;
    const int q8  = q * 8;

    // Frag-set base pointers (rows clamped to S-1; clamped cols are excluded
    // value-side by the t0+gcol<S guard, never cross batch).
    const float* fb[4];
#pragma unroll
    for (int o = 0; o < 4; ++o) {
        int t = t0 + o * 16 + m16;
        if (t > S_ - 1) t = S_ - 1;
        fb[o] = h + ((size_t)b * S_ + t) * D_ + q8;
    }

    floatx4 acc[8];
#pragma unroll
    for (int j = 0; j < 8; ++j) acc[j] = (floatx4){0.f, 0.f, 0.f, 0.f};

#pragma unroll
    for (int kk = 0; kk < 16; ++kk) {
        short8 f[4];
#pragma unroll
        for (int o = 0; o < 4; ++o) {
            float4 x = *(const float4*)(fb[o] + kk * 32);
            float4 y = *(const float4*)(fb[o] + kk * 32 + 4);
            union { uint4 u4; short8 s8; } cv;
            cv.u4.x = pk(x.x, x.y);
            cv.u4.y = pk(x.z, x.w);
            cv.u4.z = pk(y.x, y.y);
            cv.u4.w = pk(y.z, y.w);
            f[o] = cv.s8;
        }
        acc[0] = __builtin_amdgcn_mfma_f32_16x16x32_bf16(f[0], f[0], acc[0], 0, 0, 0);
        acc[1] = __builtin_amdgcn_mfma_f32_16x16x32_bf16(f[0], f[1], acc[1], 0, 0, 0);
        acc[2] = __builtin_amdgcn_mfma_f32_16x16x32_bf16(f[0], f[2], acc[2], 0, 0, 0);
        acc[3] = __builtin_amdgcn_mfma_f32_16x16x32_bf16(f[1], f[1], acc[3], 0, 0, 0);
        acc[4] = __builtin_amdgcn_mfma_f32_16x16x32_bf16(f[1], f[2], acc[4], 0, 0, 0);
        acc[5] = __builtin_amdgcn_mfma_f32_16x16x32_bf16(f[1], f[3], acc[5], 0, 0, 0);
        acc[6] = __builtin_amdgcn_mfma_f32_16x16x32_bf16(f[2], f[2], acc[6], 0, 0, 0);
        acc[7] = __builtin_amdgcn_mfma_f32_16x16x32_bf16(f[3], f[3], acc[7], 0, 0, 0);
    }

    // Diag -> per-wave norms (C/D layout: col=lane&15, row=q*4+r; diag lane
    // has q*4+r == m16, each col written exactly once).
    const int DJ[4] = {0, 3, 6, 7};
    const int DB[4] = {0, 16, 32, 48};
#pragma unroll
    for (int d = 0; d < 4; ++d) {
#pragma unroll
        for (int r = 0; r < 4; ++r)
            if (q * 4 + r == m16) nlds[w][DB[d] + m16] = sqrtf(acc[DJ[d]][r]);
    }
    __syncthreads();  // orders intra-wave LDS write->read conservatively

    // Sim terms. Tiles partition (grow,gcol) space (disjoint A/B ranges), so
    // the generic k-filter gives exact coverage with no double count.
    const float w1 = 1.0f / ((float)B_ * (float)(S_ - 1));
    const float w2 = 1.0f / ((float)B_ * (float)(10 * S_ - 145));
    const int SA[6] = {0, 0, 0, 16, 16, 16};
    const int SB[6] = {0, 16, 32, 16, 32, 48};
    float local = 0.f;
#pragma unroll
    for (int s2 = 0; s2 < 6; ++s2) {
        const int gcol = SB[s2] + m16;
        if (t0 + gcol < S_) {
            const float nb = nlds[w][gcol];
#pragma unroll
            for (int r = 0; r < 4; ++r) {
                const int grow = SA[s2] + q * 4 + r;
                const int k = gcol - grow;
                if (k == 1 || (k >= 10 && k <= 19)) {
                    const float sim = acc[s2][r] / fmaxf(nlds[w][grow] * nb, EPS);
                    local += (k == 1) ? w1 * (1.0f - sim)
                                      : w2 * fmaxf(MARGIN - sim, 0.f);
                }
            }
        }
    }

    local = wave_sum63(local);
    if (lane == 63) ws[gw] = local;  // every wave writes its own slot
}

__global__ __launch_bounds__(1024) void tcl_final(const float* __restrict__ ws,
                                                  float* __restrict__ out) {
    float v = 0.f;
    for (int j = threadIdx.x; j < NW; j += 1024) v += ws[j];
    v = wave_sum63(v);
    __shared__ float s[16];
    if ((threadIdx.x & 63) == 63) s[threadIdx.x >> 6] = v;
    __syncthreads();
    if (threadIdx.x == 0) {
        float t = 0.f;
#pragma unroll
        for (int j = 0; j < 16; j++) t += s[j];
        out[0] = t;
    }
}

extern "C" void kernel_launch(void* const* d_in, const int* in_sizes, int n_in,
                              void* d_out, int out_size, void* d_ws, size_t ws_size,
                              hipStream_t stream) {
    const float* h = (const float*)d_in[0];
    float* out = (float*)d_out;
    float* ws = (float*)d_ws;  // NW * 4 = 8 KB
    tcl_partial<<<NBLK, 256, 0, stream>>>(h, ws);
    tcl_final<<<1, 1024, 0, stream>>>(ws, out);
}